// Round 15
// baseline (318.610 us; speedup 1.0000x reference)
//
#include <hip/hip_runtime.h>
#include <hip/hip_bf16.h>

typedef __bf16 bf16_t;
typedef __bf16 bf16x4 __attribute__((ext_vector_type(4)));
typedef __bf16 bf16x8 __attribute__((ext_vector_type(8)));
typedef float f32x4 __attribute__((ext_vector_type(4)));

#define Bb 4
#define Ss 2048
#define Dd 1024
#define Hh 16
#define HDd 64

// attention scale folded into Q at GEMM1 epilogue: 1/8 * log2(e)
#define QSC 0.1803368801111244f

// async global->LDS, 16B per lane. LDS dest must be wave-uniform base + lane*16.
__device__ __forceinline__ void gld16(const bf16_t* g, bf16_t* l) {
  __builtin_amdgcn_global_load_lds(
      (const __attribute__((address_space(1))) unsigned int*)g,
      (__attribute__((address_space(3))) unsigned int*)l, 16, 0, 0);
}

// ---------------------------------------------------------------- prep
// Fused: conv_to_bf16 (blocks 0..8191) + w_qkv transpose (blocks 8192..11263).
__global__ __launch_bounds__(256) void prep(
    const float* __restrict__ x, bf16_t* __restrict__ Xc,
    const float* __restrict__ w_qkv, bf16_t* __restrict__ Wt1) {
  __shared__ bf16_t tile[32][33];
  const int b = blockIdx.x;
  const int tid = threadIdx.x;
  if (b < 8192) {
    int i = (b * 256 + tid) * 4;
    float4 v = *(const float4*)&x[i];
    bf16x4 o = {(bf16_t)v.x, (bf16_t)v.y, (bf16_t)v.z, (bf16_t)v.w};
    *(bf16x4*)&Xc[i] = o;
  } else {
    const int id = b - 8192;           // 0..3071 = 96 x 32 tiles
    const int c0 = (id % 96) * 32, r0 = (id / 96) * 32;
    const int tx = tid & 31, ty = tid >> 5;   // 32 x 8
#pragma unroll
    for (int j = 0; j < 32; j += 8)
      tile[ty + j][tx] = (bf16_t)w_qkv[(size_t)(r0 + ty + j) * 3072 + c0 + tx];
    __syncthreads();
#pragma unroll
    for (int j = 0; j < 32; j += 8)
      Wt1[(size_t)(c0 + ty + j) * 1024 + r0 + tx] = tile[tx][ty + j];
  }
}

// ---------------------------------------------------------------- transpose
__global__ __launch_bounds__(256) void transpose_conv(
    const float* __restrict__ in, bf16_t* __restrict__ out, int R, int C) {
  __shared__ bf16_t tile[32][33];
  int c0 = blockIdx.x * 32, r0 = blockIdx.y * 32;
  int tx = threadIdx.x, ty = threadIdx.y;  // 32 x 8
#pragma unroll
  for (int j = 0; j < 32; j += 8)
    tile[ty + j][tx] = (bf16_t)in[(size_t)(r0 + ty + j) * C + c0 + tx];
  __syncthreads();
#pragma unroll
  for (int j = 0; j < 32; j += 8)
    out[(size_t)(c0 + ty + j) * R + r0 + tx] = tile[tx][ty + j];
}

// ---------------------------------------------------------------- GEMM 8-phase
// Best-measured GEMM across 5 structural variants (74.2-75.5us, MfmaUtil
// 27.5% — session ceiling). GEMM1 + GEMM2. BM=256, BN=128, BK=64, 3-slot
// LDS ring (144 KiB), 512 threads = 8 waves (4M x 2N), per-wave 64x64.
// Counted vmcnt(6) at tile boundary only; XOR swizzle (0-conflict).
template <int MODE>
__global__ __launch_bounds__(512, 2) void gemm_8p(
    const bf16_t* __restrict__ A, const bf16_t* __restrict__ Bt,
    const float* __restrict__ bias, float* __restrict__ outf,
    bf16_t* __restrict__ out0, bf16_t* __restrict__ out1,
    bf16_t* __restrict__ out2, int M, int N, int K) {
  const int tid = threadIdx.x;        // 0..511
  const int lane = tid & 63;
  const int wave = tid >> 6;          // 0..7
  const int quad = lane >> 4;
  const int lr = lane & 15;
  const int wr = wave >> 1;           // 0..3 (M quarter, 64 rows)
  const int wc = wave & 1;            // 0..1 (N half, 64 cols)
  const int m0 = blockIdx.y * 256;
  const int n0 = blockIdx.x * 128;

  __shared__ __align__(16) bf16_t As[3][256 * 64];  // 96 KiB
  __shared__ __align__(16) bf16_t Bs[3][128 * 64];  // 48 KiB

  const f32x4 zero = {0.f, 0.f, 0.f, 0.f};
  f32x4 acc[4][4];
#pragma unroll
  for (int mi = 0; mi < 4; ++mi)
#pragma unroll
    for (int ni = 0; ni < 4; ++ni) acc[mi][ni] = zero;

  int ar[4], ac[4], br[2], bc[2];
#pragma unroll
  for (int i = 0; i < 4; ++i) {
    int c = tid + i * 512;
    ar[i] = c >> 3;
    ac[i] = ((c & 7) ^ (ar[i] & 7)) * 8;
  }
#pragma unroll
  for (int i = 0; i < 2; ++i) {
    int c = tid + i * 512;
    br[i] = c >> 3;
    bc[i] = ((c & 7) ^ (br[i] & 7)) * 8;
  }

  const int nk = K >> 6;

  auto stageA = [&](int t, int s) {
    const int ko = t << 6;
#pragma unroll
    for (int i = 0; i < 4; ++i)
      gld16(&A[(size_t)(m0 + ar[i]) * K + ko + ac[i]],
            &As[s][(tid + i * 512) * 8]);
  };
  auto stageB = [&](int t, int s) {
    const int ko = t << 6;
#pragma unroll
    for (int i = 0; i < 2; ++i)
      gld16(&Bt[(size_t)(n0 + br[i]) * K + ko + bc[i]],
            &Bs[s][(tid + i * 512) * 8]);
  };

  stageA(0, 0); stageB(0, 0);
  stageA(1, 1); stageB(1, 1);
  asm volatile("s_waitcnt vmcnt(6)" ::: "memory");
  __builtin_amdgcn_s_barrier();

  const int sx = lr & 7;
  const int arow = wr * 64 + lr;
  const int brow = wc * 64 + lr;

  int scur = 0;
  for (int t = 0; t < nk; ++t) {
    const bf16_t* as = As[scur];
    const bf16_t* bs = Bs[scur];
    int s2 = scur + 2;
    if (s2 >= 3) s2 -= 3;
    const bool pre = (t + 2 < nk);
#pragma unroll
    for (int ks = 0; ks < 2; ++ks) {
      bf16x8 af[4], bfr[4];
      const int cx = (((ks << 2) | quad) ^ sx) * 8;
#pragma unroll
      for (int mi = 0; mi < 4; ++mi)
        af[mi] = *(const bf16x8*)&as[(arow + mi * 16) * 64 + cx];
#pragma unroll
      for (int ni = 0; ni < 4; ++ni)
        bfr[ni] = *(const bf16x8*)&bs[(brow + ni * 16) * 64 + cx];
      if (ks == 0) {
        if (pre) stageA(t + 2, s2);
      } else {
        if (pre) stageB(t + 2, s2);
      }
      __builtin_amdgcn_s_barrier();
      asm volatile("s_waitcnt lgkmcnt(0)" ::: "memory");
      __builtin_amdgcn_sched_barrier(0);
      __builtin_amdgcn_s_setprio(1);
#pragma unroll
      for (int mi = 0; mi < 4; ++mi)
#pragma unroll
        for (int ni = 0; ni < 4; ++ni)
          acc[mi][ni] = __builtin_amdgcn_mfma_f32_16x16x32_bf16(
              af[mi], bfr[ni], acc[mi][ni], 0, 0, 0);
      __builtin_amdgcn_s_setprio(0);
      if (ks == 0) {
        __builtin_amdgcn_s_barrier();
      } else if (t + 1 < nk) {
        if (pre)
          asm volatile("s_waitcnt vmcnt(6)" ::: "memory");
        else
          asm volatile("s_waitcnt vmcnt(0)" ::: "memory");
        __builtin_amdgcn_s_barrier();
      }
    }
    scur = (scur == 2) ? 0 : scur + 1;
  }

  // Epilogue. C/D layout: col = lane&15, row = quad*4 + r.
#pragma unroll
  for (int mi = 0; mi < 4; ++mi) {
    const int mbase = m0 + wr * 64 + mi * 16 + quad * 4;
#pragma unroll
    for (int ni = 0; ni < 4; ++ni) {
      const int n = n0 + wc * 64 + ni * 16 + lr;
      const float bv = bias[n];
      if (MODE == 1) {
#pragma unroll
        for (int r = 0; r < 4; ++r)
          outf[(size_t)(mbase + r) * N + n] = acc[mi][ni][r] + bv;
      } else {
        const int which = n >> 10;
        const int h = (n >> 6) & 15;
        const int hd = n & 63;
        const int b = mbase >> 11;
        const int s = mbase & 2047;
        if (which == 2) {
          bf16x4 pk = {(bf16_t)(acc[mi][ni][0] + bv),
                       (bf16_t)(acc[mi][ni][1] + bv),
                       (bf16_t)(acc[mi][ni][2] + bv),
                       (bf16_t)(acc[mi][ni][3] + bv)};
          *(bf16x4*)&out2[(((size_t)(b * Hh + h)) * HDd + hd) * Ss + s] = pk;
        } else {
          bf16_t* dst = (which == 0) ? out0 : out1;
          const float sc2 = (which == 0) ? QSC : 1.0f;
#pragma unroll
          for (int r = 0; r < 4; ++r)
            dst[(((size_t)(b * Hh + h)) * Ss + s + r) * HDd + hd] =
                (bf16_t)((acc[mi][ni][r] + bv) * sc2);
        }
      }
    }
  }
}

// ---------------------------------------------------------------- attention
// BARRIER-FREE rewrite. r14 showed attn (~64us) is serial-chain-bound, not
// pipe-bound (~15us of pipe work): the chain was ds_write K/V -> barrier ->
// ds_read -> lgkm -> QK -> SM -> Ps -> PV with 2 waves/SIMD.
// K and V fragments are loadable DIRECTLY from global in MFMA A-frag layout
// (16B contiguous): K[kbase+kt4*16+lr][kk2*32+quad*8], V^T[dt*16+lr][kbase+
// kk2*32+quad*8]. Each wave loads its own copy (4x redundancy -> L2, all
// sharers XCD-colocated by the bid mapping). NO __syncthreads at all:
// K double-buffered in registers (ping-pong macro, static indices), V
// loaded just-in-time (compiler inserts counted vmcnt for reg loads
// automatically). LDS = Ps only (16KB). Keeps: pair balance, XCD mapping,
// swizzled Ps, kk2-interleaved SM/PV (r14's verified win).
__global__ __launch_bounds__(256, 2) void attn_kernel(
    const bf16_t* __restrict__ Qg, const bf16_t* __restrict__ Kg,
    const bf16_t* __restrict__ Vtg, bf16_t* __restrict__ Og) {
  const int tid = threadIdx.x;
  const int lane = tid & 63;
  const int wave = tid >> 6;
  const int quad = lane >> 4;
  const int lr = lane & 15;
  const int l7 = lr & 7;

  const int bid = blockIdx.x;        // 0..511
  const int xcd = bid & 7;
  const int j = bid >> 3;            // 0..63
  const int bh = xcd * 8 + (j >> 3); // 8 bh per XCD
  const int p = j & 7;               // pair index 0..7
  const int b = bh >> 4;
  const int h = bh & 15;
  const int wq = wave * 32;

  const bf16_t* Qp = Qg + (size_t)bh * Ss * HDd;   // [s][d] (pre-scaled)
  const bf16_t* Kp = Kg + (size_t)bh * Ss * HDd;   // [s][d]
  const bf16_t* Vp = Vtg + (size_t)bh * HDd * Ss;  // [d][s]

  __shared__ bf16_t Ps[4][32 * 64];    // per-wave P [q][key], swizzled rows

  const f32x4 zero = {0.f, 0.f, 0.f, 0.f};

  // per-lane fragment base offsets
  // K frag (kt4,kk2): Kp[(kbase + kt4*16 + lr)*64 + kk2*32 + quad*8]
  // V frag (dt ,kk2): Vp[(dt*16 + lr)*Ss + kbase + kk2*32 + quad*8]
  const int kfo = lr * HDd + quad * 8;           // + kt4*1024 + kk2*32 + kbase*64
  const size_t vfo = (size_t)lr * Ss + quad * 8; // + dt*16*Ss + kk2*32 + kbase

  for (int half = 0; half < 2; ++half) {
    const int qt = half ? p : 15 - p;
    const int qbase = qt * 128;
    const int ktiles = qt * 2 + 2;

    bf16x8 bq[2][2];
#pragma unroll
    for (int qt2 = 0; qt2 < 2; ++qt2)
#pragma unroll
      for (int kk2 = 0; kk2 < 2; ++kk2)
        bq[qt2][kk2] = *(const bf16x8*)&Qp[(size_t)(qbase + wq + qt2 * 16 +
                                                    lr) *
                                               HDd +
                                           kk2 * 32 + quad * 8];

    f32x4 oacc[4][2];
#pragma unroll
    for (int dt = 0; dt < 4; ++dt)
#pragma unroll
      for (int qt2 = 0; qt2 < 2; ++qt2) oacc[dt][qt2] = zero;
    float l_run[2] = {0.f, 0.f};

    // K register double-buffer
    bf16x8 ka[4][2], kb_[4][2];
#pragma unroll
    for (int kt4 = 0; kt4 < 4; ++kt4)
#pragma unroll
      for (int kk2 = 0; kk2 < 2; ++kk2)
        ka[kt4][kk2] =
            *(const bf16x8*)&Kp[(size_t)(kt4 * 16) * HDd + kk2 * 32 + kfo];

    // one k-tile body: uses KC for QK, prefetches K(KT+1) into KN.
#define ATTN_BODY(KT, KC, KN)                                                 \
  {                                                                           \
    const int kbase = (KT)*64;                                                \
    const int nkb = ((KT) + 1 < ktiles) ? kbase + 64 : 0;                     \
    /* prefetch next K tile into KN */                                        \
    _Pragma("unroll") for (int kt4 = 0; kt4 < 4; ++kt4)                       \
        _Pragma("unroll") for (int kk2 = 0; kk2 < 2; ++kk2)                   \
        KN[kt4][kk2] = *(const bf16x8*)&Kp[(size_t)(nkb + kt4 * 16) * HDd +   \
                                           kk2 * 32 + kfo];                   \
    /* V fragments for this tile (just-in-time; used after QK+SM) */          \
    bf16x8 vf[4][2];                                                          \
    _Pragma("unroll") for (int dt = 0; dt < 4; ++dt)                          \
        _Pragma("unroll") for (int kk2 = 0; kk2 < 2; ++kk2)                   \
        vf[dt][kk2] =                                                         \
            *(const bf16x8*)&Vp[(size_t)(dt * 16) * Ss + kbase + kk2 * 32 +   \
                                vfo];                                         \
    /* QK^T: 16 MFMA */                                                       \
    f32x4 sacc[4][2];                                                         \
    _Pragma("unroll") for (int kt4 = 0; kt4 < 4; ++kt4)                       \
        _Pragma("unroll") for (int qt2 = 0; qt2 < 2; ++qt2) sacc[kt4][qt2] =  \
        zero;                                                                 \
    _Pragma("unroll") for (int kk2 = 0; kk2 < 2; ++kk2)                       \
        _Pragma("unroll") for (int kt4 = 0; kt4 < 4; ++kt4)                   \
        _Pragma("unroll") for (int qt2 = 0; qt2 < 2; ++qt2) sacc[kt4][qt2] =  \
        __builtin_amdgcn_mfma_f32_16x16x32_bf16(KC[kt4][kk2], bq[qt2][kk2],   \
                                                sacc[kt4][qt2], 0, 0, 0);     \
    const bool edge = ((KT) >= 2 * qt);                                       \
    /* interleaved SM/Ps/PV (r14 win): PV(kk2) after SM slices 2kk2,2kk2+1 */ \
    _Pragma("unroll") for (int kk2 = 0; kk2 < 2; ++kk2) {                     \
      _Pragma("unroll") for (int k4 = 0; k4 < 2; ++k4) {                      \
        const int kt4 = kk2 * 2 + k4;                                         \
        const int psl = ((kt4 * 2 + (quad >> 1)) ^ l7) * 8 + (quad & 1) * 4;  \
        _Pragma("unroll") for (int qt2 = 0; qt2 < 2; ++qt2) {                 \
          _Pragma("unroll") for (int r = 0; r < 4; ++r) {                     \
            float s = sacc[kt4][qt2][r];                                      \
            if (edge) {                                                       \
              const int qg = qbase + wq + qt2 * 16 + lr;                      \
              const int kg = kbase + kt4 * 16 + quad * 4 + r;                 \
              if (kg > qg) s = -1e30f;                                        \
            }                                                                 \
            const float pv = __builtin_amdgcn_exp2f(s);                       \
            sacc[kt4][qt2][r] = pv;                                           \
            l_run[qt2] += pv;                                                 \
          }                                                                   \
          bf16x4 pk = {(bf16_t)sacc[kt4][qt2][0], (bf16_t)sacc[kt4][qt2][1],  \
                       (bf16_t)sacc[kt4][qt2][2], (bf16_t)sacc[kt4][qt2][3]}; \
          *(bf16x4*)&Ps[wave][(qt2 * 16 + lr) * 64 + psl] = pk;               \
        }                                                                     \
      }                                                                       \
      const int rsl = (((kk2 << 2) | quad) ^ l7) * 8;                         \
      bf16x8 bp[2];                                                           \
      _Pragma("unroll") for (int qt2 = 0; qt2 < 2; ++qt2) bp[qt2] =           \
          *(const bf16x8*)&Ps[wave][(qt2 * 16 + lr) * 64 + rsl];              \
      _Pragma("unroll") for (int dt = 0; dt < 4; ++dt)                        \
          _Pragma("unroll") for (int qt2 = 0; qt2 < 2; ++qt2) oacc[dt][qt2] = \
          __builtin_amdgcn_mfma_f32_16x16x32_bf16(vf[dt][kk2], bp[qt2],       \
                                                  oacc[dt][qt2], 0, 0, 0);    \
    }                                                                         \
  }

    // ktiles is always even (qt*2+2): clean ping-pong, all static indices.
    for (int kt = 0; kt < ktiles; kt += 2) {
      ATTN_BODY(kt, ka, kb_);
      ATTN_BODY(kt + 1, kb_, ka);
    }
#undef ATTN_BODY

#pragma unroll
    for (int qt2 = 0; qt2 < 2; ++qt2) {
      l_run[qt2] += __shfl_xor(l_run[qt2], 16, 64);
      l_run[qt2] += __shfl_xor(l_run[qt2], 32, 64);
    }

#pragma unroll
    for (int qt2 = 0; qt2 < 2; ++qt2) {
      const float inv = 1.f / l_run[qt2];
      const int qg = qbase + wq + qt2 * 16 + lr;
#pragma unroll
      for (int dt = 0; dt < 4; ++dt) {
        bf16x4 ov = {(bf16_t)(oacc[dt][qt2][0] * inv),
                     (bf16_t)(oacc[dt][qt2][1] * inv),
                     (bf16_t)(oacc[dt][qt2][2] * inv),
                     (bf16_t)(oacc[dt][qt2][3] * inv)};
        *(bf16x4*)&Og[((size_t)b * Ss + qg) * Dd + h * HDd + dt * 16 +
                      quad * 4] = ov;
      }
    }
  }
}

// ---------------------------------------------------------------- launch
extern "C" void kernel_launch(void* const* d_in, const int* in_sizes, int n_in,
                              void* d_out, int out_size, void* d_ws,
                              size_t ws_size, hipStream_t stream) {
  const float* x = (const float*)d_in[0];       // [4,2048,1024] fp32
  const float* w_qkv = (const float*)d_in[1];   // [1024,3072]
  const float* b_qkv = (const float*)d_in[2];   // [3072]
  const float* w_out = (const float*)d_in[3];   // [1024,1024]
  const float* b_out = (const float*)d_in[4];   // [1024]
  float* out = (float*)d_out;                   // [4,2048,1024] fp32 (32 MB)

  bf16_t* Kb = (bf16_t*)d_ws;                    // [B,H,S,HD] 16 MB
  bf16_t* Vt = Kb + (size_t)Bb * Hh * Ss * HDd;  // [B,H,HD,S] 16 MB
  bf16_t* slot3 = Vt + (size_t)Bb * Hh * Ss * HDd;
  bf16_t* Wt1 = slot3;                           // [3072,1024] 6 MB
  bf16_t* Ob = slot3;                            // [8192,1024] 16 MB
  bf16_t* Wt2 = Kb;                              // [1024,1024] 2 MB (post-attn)
  bf16_t* Qb = (bf16_t*)d_out;                   // [B,H,S,HD]
  bf16_t* Xc = (bf16_t*)d_out + (size_t)8192 * 1024;  // [8192,1024] bf16

  // fused conv + w_qkv transpose (8192 + 3072 blocks)
  prep<<<11264, 256, 0, stream>>>(x, Xc, w_qkv, Wt1);

  // GEMM1: 24x32 = 768 blocks = 3 exact rounds of 256 CUs.
  gemm_8p<0><<<dim3(24, 32), 512, 0, stream>>>(
      Xc, Wt1, b_qkv, nullptr, Qb, Kb, Vt, 8192, 3072, 1024);

  attn_kernel<<<dim3(512), 256, 0, stream>>>(Qb, Kb, Vt, Ob);

  transpose_conv<<<dim3(32, 32), dim3(32, 8), 0, stream>>>(w_out, Wt2, 1024,
                                                           1024);

  // GEMM2: 8x32 = 256 blocks = 1 per CU, uniform single round.
  gemm_8p<1><<<dim3(8, 32), 512, 0, stream>>>(
      Ob, Wt2, b_out, out, nullptr, nullptr, nullptr, 8192, 1024, 1024);
}

// Round 16
// 253.376 us; speedup vs baseline: 1.2575x; 1.2575x over previous
//
#include <hip/hip_runtime.h>
#include <hip/hip_bf16.h>

typedef __bf16 bf16_t;
typedef __bf16 bf16x4 __attribute__((ext_vector_type(4)));
typedef __bf16 bf16x8 __attribute__((ext_vector_type(8)));
typedef float f32x4 __attribute__((ext_vector_type(4)));

#define Bb 4
#define Ss 2048
#define Dd 1024
#define Hh 16
#define HDd 64

// attention scale folded into Q at GEMM1 epilogue: 1/8 * log2(e)
#define QSC 0.1803368801111244f

// async global->LDS, 16B per lane. LDS dest must be wave-uniform base + lane*16.
__device__ __forceinline__ void gld16(const bf16_t* g, bf16_t* l) {
  __builtin_amdgcn_global_load_lds(
      (const __attribute__((address_space(1))) unsigned int*)g,
      (__attribute__((address_space(3))) unsigned int*)l, 16, 0, 0);
}

// ---------------------------------------------------------------- prep
// Fused: conv_to_bf16 (blocks 0..8191) + w_qkv transpose (blocks 8192..11263).
__global__ __launch_bounds__(256) void prep(
    const float* __restrict__ x, bf16_t* __restrict__ Xc,
    const float* __restrict__ w_qkv, bf16_t* __restrict__ Wt1) {
  __shared__ bf16_t tile[32][33];
  const int b = blockIdx.x;
  const int tid = threadIdx.x;
  if (b < 8192) {
    int i = (b * 256 + tid) * 4;
    float4 v = *(const float4*)&x[i];
    bf16x4 o = {(bf16_t)v.x, (bf16_t)v.y, (bf16_t)v.z, (bf16_t)v.w};
    *(bf16x4*)&Xc[i] = o;
  } else {
    const int id = b - 8192;           // 0..3071 = 96 x 32 tiles
    const int c0 = (id % 96) * 32, r0 = (id / 96) * 32;
    const int tx = tid & 31, ty = tid >> 5;   // 32 x 8
#pragma unroll
    for (int j = 0; j < 32; j += 8)
      tile[ty + j][tx] = (bf16_t)w_qkv[(size_t)(r0 + ty + j) * 3072 + c0 + tx];
    __syncthreads();
#pragma unroll
    for (int j = 0; j < 32; j += 8)
      Wt1[(size_t)(c0 + ty + j) * 1024 + r0 + tx] = tile[tx][ty + j];
  }
}

// ---------------------------------------------------------------- transpose
__global__ __launch_bounds__(256) void transpose_conv(
    const float* __restrict__ in, bf16_t* __restrict__ out, int R, int C) {
  __shared__ bf16_t tile[32][33];
  int c0 = blockIdx.x * 32, r0 = blockIdx.y * 32;
  int tx = threadIdx.x, ty = threadIdx.y;  // 32 x 8
#pragma unroll
  for (int j = 0; j < 32; j += 8)
    tile[ty + j][tx] = (bf16_t)in[(size_t)(r0 + ty + j) * C + c0 + tx];
  __syncthreads();
#pragma unroll
  for (int j = 0; j < 32; j += 8)
    out[(size_t)(c0 + ty + j) * R + r0 + tx] = tile[tx][ty + j];
}

// ---------------------------------------------------------------- GEMM 8-phase
// Best-measured GEMM across 5 structural variants (74.2-75.5us, MfmaUtil
// 27.5% — session ceiling; per-wave 64x64/128x64, ring depth, occupancy,
// and swizzle variations all land 22-27.5%). GEMM1 + GEMM2.
// BM=256, BN=128, BK=64, 3-slot LDS ring (144 KiB), 512 threads = 8 waves
// (4M x 2N), per-wave 64x64. Per K-tile: 2 phases of {8 ds_read_b128 ->
// stage issue -> barrier -> lgkmcnt(0) -> setprio(1) 16 MFMA setprio(0) ->
// barrier}; counted vmcnt(6) at tile boundary only. XOR swizzle (0-conflict,
// measured r4/r6/r8/r11/r14): stored chunk q^(row&7), pre-swizzled source.
template <int MODE>
__global__ __launch_bounds__(512, 2) void gemm_8p(
    const bf16_t* __restrict__ A, const bf16_t* __restrict__ Bt,
    const float* __restrict__ bias, float* __restrict__ outf,
    bf16_t* __restrict__ out0, bf16_t* __restrict__ out1,
    bf16_t* __restrict__ out2, int M, int N, int K) {
  const int tid = threadIdx.x;        // 0..511
  const int lane = tid & 63;
  const int wave = tid >> 6;          // 0..7
  const int quad = lane >> 4;
  const int lr = lane & 15;
  const int wr = wave >> 1;           // 0..3 (M quarter, 64 rows)
  const int wc = wave & 1;            // 0..1 (N half, 64 cols)
  const int m0 = blockIdx.y * 256;
  const int n0 = blockIdx.x * 128;

  __shared__ __align__(16) bf16_t As[3][256 * 64];  // 96 KiB
  __shared__ __align__(16) bf16_t Bs[3][128 * 64];  // 48 KiB

  const f32x4 zero = {0.f, 0.f, 0.f, 0.f};
  f32x4 acc[4][4];
#pragma unroll
  for (int mi = 0; mi < 4; ++mi)
#pragma unroll
    for (int ni = 0; ni < 4; ++ni) acc[mi][ni] = zero;

  int ar[4], ac[4], br[2], bc[2];
#pragma unroll
  for (int i = 0; i < 4; ++i) {
    int c = tid + i * 512;
    ar[i] = c >> 3;
    ac[i] = ((c & 7) ^ (ar[i] & 7)) * 8;
  }
#pragma unroll
  for (int i = 0; i < 2; ++i) {
    int c = tid + i * 512;
    br[i] = c >> 3;
    bc[i] = ((c & 7) ^ (br[i] & 7)) * 8;
  }

  const int nk = K >> 6;

  auto stageA = [&](int t, int s) {
    const int ko = t << 6;
#pragma unroll
    for (int i = 0; i < 4; ++i)
      gld16(&A[(size_t)(m0 + ar[i]) * K + ko + ac[i]],
            &As[s][(tid + i * 512) * 8]);
  };
  auto stageB = [&](int t, int s) {
    const int ko = t << 6;
#pragma unroll
    for (int i = 0; i < 2; ++i)
      gld16(&Bt[(size_t)(n0 + br[i]) * K + ko + bc[i]],
            &Bs[s][(tid + i * 512) * 8]);
  };

  stageA(0, 0); stageB(0, 0);
  stageA(1, 1); stageB(1, 1);
  asm volatile("s_waitcnt vmcnt(6)" ::: "memory");
  __builtin_amdgcn_s_barrier();

  const int sx = lr & 7;
  const int arow = wr * 64 + lr;
  const int brow = wc * 64 + lr;

  int scur = 0;
  for (int t = 0; t < nk; ++t) {
    const bf16_t* as = As[scur];
    const bf16_t* bs = Bs[scur];
    int s2 = scur + 2;
    if (s2 >= 3) s2 -= 3;
    const bool pre = (t + 2 < nk);
#pragma unroll
    for (int ks = 0; ks < 2; ++ks) {
      bf16x8 af[4], bfr[4];
      const int cx = (((ks << 2) | quad) ^ sx) * 8;
#pragma unroll
      for (int mi = 0; mi < 4; ++mi)
        af[mi] = *(const bf16x8*)&as[(arow + mi * 16) * 64 + cx];
#pragma unroll
      for (int ni = 0; ni < 4; ++ni)
        bfr[ni] = *(const bf16x8*)&bs[(brow + ni * 16) * 64 + cx];
      if (ks == 0) {
        if (pre) stageA(t + 2, s2);
      } else {
        if (pre) stageB(t + 2, s2);
      }
      __builtin_amdgcn_s_barrier();
      asm volatile("s_waitcnt lgkmcnt(0)" ::: "memory");
      __builtin_amdgcn_sched_barrier(0);
      __builtin_amdgcn_s_setprio(1);
#pragma unroll
      for (int mi = 0; mi < 4; ++mi)
#pragma unroll
        for (int ni = 0; ni < 4; ++ni)
          acc[mi][ni] = __builtin_amdgcn_mfma_f32_16x16x32_bf16(
              af[mi], bfr[ni], acc[mi][ni], 0, 0, 0);
      __builtin_amdgcn_s_setprio(0);
      if (ks == 0) {
        __builtin_amdgcn_s_barrier();
      } else if (t + 1 < nk) {
        if (pre)
          asm volatile("s_waitcnt vmcnt(6)" ::: "memory");
        else
          asm volatile("s_waitcnt vmcnt(0)" ::: "memory");
        __builtin_amdgcn_s_barrier();
      }
    }
    scur = (scur == 2) ? 0 : scur + 1;
  }

  // Epilogue. C/D layout: col = lane&15, row = quad*4 + r.
#pragma unroll
  for (int mi = 0; mi < 4; ++mi) {
    const int mbase = m0 + wr * 64 + mi * 16 + quad * 4;
#pragma unroll
    for (int ni = 0; ni < 4; ++ni) {
      const int n = n0 + wc * 64 + ni * 16 + lr;
      const float bv = bias[n];
      if (MODE == 1) {
#pragma unroll
        for (int r = 0; r < 4; ++r)
          outf[(size_t)(mbase + r) * N + n] = acc[mi][ni][r] + bv;
      } else {
        const int which = n >> 10;
        const int h = (n >> 6) & 15;
        const int hd = n & 63;
        const int b = mbase >> 11;
        const int s = mbase & 2047;
        if (which == 2) {
          bf16x4 pk = {(bf16_t)(acc[mi][ni][0] + bv),
                       (bf16_t)(acc[mi][ni][1] + bv),
                       (bf16_t)(acc[mi][ni][2] + bv),
                       (bf16_t)(acc[mi][ni][3] + bv)};
          *(bf16x4*)&out2[(((size_t)(b * Hh + h)) * HDd + hd) * Ss + s] = pk;
        } else {
          bf16_t* dst = (which == 0) ? out0 : out1;
          const float sc2 = (which == 0) ? QSC : 1.0f;
#pragma unroll
          for (int r = 0; r < 4; ++r)
            dst[(((size_t)(b * Hh + h)) * Ss + s + r) * HDd + hd] =
                (bf16_t)((acc[mi][ni][r] + bv) * sc2);
        }
      }
    }
  }
}

// ---------------------------------------------------------------- attention
// r14 BEST-MEASURED version (251.6us total; attn ~64us), restored verbatim.
// Structure: pair-balanced (34 ktiles/block), XCD-mapped bids, double-
// buffered LDS K/V staging (shared across 4 waves — r15 proved per-wave
// global re-reads are 2x worse), XOR-chunk swizzle (conflicts 7.8M->2.2M),
// VALU l_run + shfl reduce (r12 proved l-via-MFMA regresses), and
// kk2-interleaved SM/Ps/PV (r14's verified -12us: PV chunk kk2 needs only
// P slices {2kk2,2kk2+1}, so SM of the next pair overlaps PV's MFMAs).
__global__ __launch_bounds__(256) void attn_kernel(
    const bf16_t* __restrict__ Qg, const bf16_t* __restrict__ Kg,
    const bf16_t* __restrict__ Vtg, bf16_t* __restrict__ Og) {
  const int tid = threadIdx.x;
  const int lane = tid & 63;
  const int wave = tid >> 6;
  const int quad = lane >> 4;
  const int lr = lane & 15;
  const int l7 = lr & 7;

  const int bid = blockIdx.x;        // 0..511
  const int xcd = bid & 7;
  const int j = bid >> 3;            // 0..63
  const int bh = xcd * 8 + (j >> 3); // 8 bh per XCD
  const int p = j & 7;               // pair index 0..7
  const int b = bh >> 4;
  const int h = bh & 15;
  const int wq = wave * 32;

  const bf16_t* Qp = Qg + (size_t)bh * Ss * HDd;   // [s][d] (pre-scaled)
  const bf16_t* Kp = Kg + (size_t)bh * Ss * HDd;   // [s][d]
  const bf16_t* Vp = Vtg + (size_t)bh * HDd * Ss;  // [d][s]

  __shared__ bf16_t Ks[2][64 * 64];    // [buf][key][d]   swizzled rows
  __shared__ bf16_t Vts[2][64 * 64];   // [buf][d][key]   swizzled rows
  __shared__ bf16_t Ps[4][32 * 64];    // per-wave P [q][key] swizzled rows

  bf16x8 kreg[2], vreg[2];
  const int r0 = tid >> 3;             // 0..31
  const int c0 = (tid & 7) * 8;        // 0..56
  const int swz = ((tid & 7) ^ ((tid >> 3) & 7)) * 8;

  const f32x4 zero = {0.f, 0.f, 0.f, 0.f};

#pragma unroll
  for (int i = 0; i < 2; ++i) {
    kreg[i] = *(const bf16x8*)&Kp[(size_t)(r0 + i * 32) * HDd + c0];
    vreg[i] = *(const bf16x8*)&Vp[(size_t)(r0 + i * 32) * Ss + c0];
  }

  int cur = 0;
  for (int half = 0; half < 2; ++half) {
    const int qt = half ? p : 15 - p;
    const int qbase = qt * 128;
    const int ktiles = qt * 2 + 2;

    bf16x8 bq[2][2];
#pragma unroll
    for (int qt2 = 0; qt2 < 2; ++qt2)
#pragma unroll
      for (int kk2 = 0; kk2 < 2; ++kk2)
        bq[qt2][kk2] = *(const bf16x8*)&Qp[(size_t)(qbase + wq + qt2 * 16 +
                                                    lr) *
                                               HDd +
                                           kk2 * 32 + quad * 8];

    f32x4 oacc[4][2];
#pragma unroll
    for (int dt = 0; dt < 4; ++dt)
#pragma unroll
      for (int qt2 = 0; qt2 < 2; ++qt2) oacc[dt][qt2] = zero;
    float l_run[2] = {0.f, 0.f};

    for (int kt = 0; kt < ktiles; ++kt) {
      const int kbase = kt * 64;

#pragma unroll
      for (int i = 0; i < 2; ++i) {
        *(bf16x8*)&Ks[cur][(r0 + i * 32) * 64 + swz] = kreg[i];
        *(bf16x8*)&Vts[cur][(r0 + i * 32) * 64 + swz] = vreg[i];
      }
      __syncthreads();

      const int nkb = (kt + 1 < ktiles) ? kbase + 64 : 0;
#pragma unroll
      for (int i = 0; i < 2; ++i) {
        kreg[i] = *(const bf16x8*)&Kp[(size_t)(nkb + r0 + i * 32) * HDd + c0];
        vreg[i] = *(const bf16x8*)&Vp[(size_t)(r0 + i * 32) * Ss + nkb + c0];
      }

      // QK^T: 16 MFMA
      f32x4 sacc[4][2];
#pragma unroll
      for (int kt4 = 0; kt4 < 4; ++kt4)
#pragma unroll
        for (int qt2 = 0; qt2 < 2; ++qt2) sacc[kt4][qt2] = zero;
#pragma unroll
      for (int kk2 = 0; kk2 < 2; ++kk2) {
        const int rsl = (((kk2 << 2) | quad) ^ l7) * 8;
        bf16x8 ak[4];
#pragma unroll
        for (int kt4 = 0; kt4 < 4; ++kt4)
          ak[kt4] = *(const bf16x8*)&Ks[cur][(kt4 * 16 + lr) * 64 + rsl];
#pragma unroll
        for (int kt4 = 0; kt4 < 4; ++kt4)
#pragma unroll
          for (int qt2 = 0; qt2 < 2; ++qt2)
            sacc[kt4][qt2] = __builtin_amdgcn_mfma_f32_16x16x32_bf16(
                ak[kt4], bq[qt2][kk2], sacc[kt4][qt2], 0, 0, 0);
      }

      const bool edge = (kt >= 2 * qt);
      // interleaved: SM slices {2kk2,2kk2+1} -> Ps -> PV(kk2)
#pragma unroll
      for (int kk2 = 0; kk2 < 2; ++kk2) {
#pragma unroll
        for (int k4 = 0; k4 < 2; ++k4) {
          const int kt4 = kk2 * 2 + k4;
          const int psl = ((kt4 * 2 + (quad >> 1)) ^ l7) * 8 + (quad & 1) * 4;
#pragma unroll
          for (int qt2 = 0; qt2 < 2; ++qt2) {
#pragma unroll
            for (int r = 0; r < 4; ++r) {
              float s = sacc[kt4][qt2][r];
              if (edge) {
                const int qg = qbase + wq + qt2 * 16 + lr;
                const int kg = kbase + kt4 * 16 + quad * 4 + r;
                if (kg > qg) s = -1e30f;
              }
              const float pv = __builtin_amdgcn_exp2f(s);
              sacc[kt4][qt2][r] = pv;
              l_run[qt2] += pv;
            }
            bf16x4 pk = {(bf16_t)sacc[kt4][qt2][0], (bf16_t)sacc[kt4][qt2][1],
                         (bf16_t)sacc[kt4][qt2][2],
                         (bf16_t)sacc[kt4][qt2][3]};
            *(bf16x4*)&Ps[wave][(qt2 * 16 + lr) * 64 + psl] = pk;
          }
        }
        // PV chunk kk2 (needs only slices 2kk2, 2kk2+1, just written)
        const int rsl = (((kk2 << 2) | quad) ^ l7) * 8;
        bf16x8 av[4], bp[2];
#pragma unroll
        for (int dt = 0; dt < 4; ++dt)
          av[dt] = *(const bf16x8*)&Vts[cur][(dt * 16 + lr) * 64 + rsl];
#pragma unroll
        for (int qt2 = 0; qt2 < 2; ++qt2)
          bp[qt2] = *(const bf16x8*)&Ps[wave][(qt2 * 16 + lr) * 64 + rsl];
#pragma unroll
        for (int dt = 0; dt < 4; ++dt)
#pragma unroll
          for (int qt2 = 0; qt2 < 2; ++qt2)
            oacc[dt][qt2] = __builtin_amdgcn_mfma_f32_16x16x32_bf16(
                av[dt], bp[qt2], oacc[dt][qt2], 0, 0, 0);
      }
      cur ^= 1;
    }

#pragma unroll
    for (int qt2 = 0; qt2 < 2; ++qt2) {
      l_run[qt2] += __shfl_xor(l_run[qt2], 16, 64);
      l_run[qt2] += __shfl_xor(l_run[qt2], 32, 64);
    }

#pragma unroll
    for (int qt2 = 0; qt2 < 2; ++qt2) {
      const float inv = 1.f / l_run[qt2];
      const int qg = qbase + wq + qt2 * 16 + lr;
#pragma unroll
      for (int dt = 0; dt < 4; ++dt) {
        bf16x4 ov = {(bf16_t)(oacc[dt][qt2][0] * inv),
                     (bf16_t)(oacc[dt][qt2][1] * inv),
                     (bf16_t)(oacc[dt][qt2][2] * inv),
                     (bf16_t)(oacc[dt][qt2][3] * inv)};
        *(bf16x4*)&Og[((size_t)b * Ss + qg) * Dd + h * HDd + dt * 16 +
                      quad * 4] = ov;
      }
    }
  }
}

// ---------------------------------------------------------------- launch
extern "C" void kernel_launch(void* const* d_in, const int* in_sizes, int n_in,
                              void* d_out, int out_size, void* d_ws,
                              size_t ws_size, hipStream_t stream) {
  const float* x = (const float*)d_in[0];       // [4,2048,1024] fp32
  const float* w_qkv = (const float*)d_in[1];   // [1024,3072]
  const float* b_qkv = (const float*)d_in[2];   // [3072]
  const float* w_out = (const float*)d_in[3];   // [1024,1024]
  const float* b_out = (const float*)d_in[4];   // [1024]
  float* out = (float*)d_out;                   // [4,2048,1024] fp32 (32 MB)

  bf16_t* Kb = (bf16_t*)d_ws;                    // [B,H,S,HD] 16 MB
  bf16_t* Vt = Kb + (size_t)Bb * Hh * Ss * HDd;  // [B,H,HD,S] 16 MB
  bf16_t* slot3 = Vt + (size_t)Bb * Hh * Ss * HDd;
  bf16_t* Wt1 = slot3;                           // [3072,1024] 6 MB
  bf16_t* Ob = slot3;                            // [8192,1024] 16 MB
  bf16_t* Wt2 = Kb;                              // [1024,1024] 2 MB (post-attn)
  bf16_t* Qb = (bf16_t*)d_out;                   // [B,H,S,HD]
  bf16_t* Xc = (bf16_t*)d_out + (size_t)8192 * 1024;  // [8192,1024] bf16

  // fused conv + w_qkv transpose (8192 + 3072 blocks)
  prep<<<11264, 256, 0, stream>>>(x, Xc, w_qkv, Wt1);

  // GEMM1: 24x32 = 768 blocks = 3 exact rounds of 256 CUs.
  gemm_8p<0><<<dim3(24, 32), 512, 0, stream>>>(
      Xc, Wt1, b_qkv, nullptr, Qb, Kb, Vt, 8192, 3072, 1024);

  attn_kernel<<<dim3(512), 256, 0, stream>>>(Qb, Kb, Vt, Ob);

  transpose_conv<<<dim3(32, 32), dim3(32, 8), 0, stream>>>(w_out, Wt2, 1024,
                                                           1024);

  // GEMM2: 8x32 = 256 blocks = 1 per CU, uniform single round.
  gemm_8p<1><<<dim3(8, 32), 512, 0, stream>>>(
      Ob, Wt2, b_out, out, nullptr, nullptr, nullptr, 8192, 1024, 1024);
}